// Round 4
// baseline (357.105 us; speedup 1.0000x reference)
//
#include <hip/hip_runtime.h>
#include <hip/hip_bf16.h>

#define T_SEQ   2048
#define HIDDEN  2880
#define NQ      64
#define NKV     8
#define HD      64
#define QSIZE   4096   // NQ*HD
#define KVSIZE  512    // NKV*HD
#define QKV_N   5120   // QSIZE + 2*KVSIZE
#define WINDOW  128
#define SCALE_F 0.125f // HD^-0.5
// log2(150000)/32
#define ROPE_L2 0.53733241958f

typedef unsigned short u16;
typedef __attribute__((ext_vector_type(8))) short short8;
typedef __attribute__((ext_vector_type(4))) float f32x4;

__device__ __forceinline__ u16 f2bf(float f) {
  __hip_bfloat16 b = __float2bfloat16(f);
  u16 u; __builtin_memcpy(&u, &b, 2); return u;
}

__device__ __forceinline__ void gload16(const u16* g, u16* l) {
  __builtin_amdgcn_global_load_lds(
      (const __attribute__((address_space(1))) void*)g,
      (__attribute__((address_space(3))) void*)l, 16, 0, 0);
}

// ---------------- prep: cast X + transpose w_qkv + transpose w_o ----------------
#define CAST_BLKS 5760            // 2048*2880/4/256
#define TQ_BX 160
#define TQ_BLKS (160 * 45)        // w_qkv: C=5120/32, R=2880/64
#define TO_BX 90
#define TO_BLKS (90 * 64)         // w_o:  C=2880/32, R=4096/64
#define PREP_BLKS (CAST_BLKS + TQ_BLKS + TO_BLKS)

__global__ void prep_kernel(const float* __restrict__ hidden,
                            const float* __restrict__ w_qkv,
                            const float* __restrict__ w_o,
                            u16* __restrict__ Xb, u16* __restrict__ Wqt,
                            u16* __restrict__ Wot) {
  __shared__ float tile[32][65];
  const int b = blockIdx.x, tid = threadIdx.x;
  if (b < CAST_BLKS) {
    int i = b * 256 + tid;
    float4 v = ((const float4*)hidden)[i];
    ushort4 o;
    o.x = f2bf(v.x); o.y = f2bf(v.y); o.z = f2bf(v.z); o.w = f2bf(v.w);
    ((ushort4*)Xb)[i] = o;
    return;
  }
  const float* in; u16* out; int R, C, bx, by;
  if (b < CAST_BLKS + TQ_BLKS) {
    int bb = b - CAST_BLKS; bx = bb % TQ_BX; by = bb / TQ_BX;
    in = w_qkv; out = Wqt; R = HIDDEN; C = QKV_N;
  } else {
    int bb = b - CAST_BLKS - TQ_BLKS; bx = bb % TO_BX; by = bb / TO_BX;
    in = w_o; out = Wot; R = QSIZE; C = HIDDEN;
  }
  const int r0 = by * 64, c0 = bx * 32;
  const int tx = tid & 31, ty = tid >> 5;
#pragma unroll
  for (int i = 0; i < 64; i += 8)
    tile[tx][ty + i] = in[(size_t)(r0 + ty + i) * C + c0 + tx];
  __syncthreads();
  const int tx2 = tid & 63, ty2 = tid >> 6;
#pragma unroll
  for (int i = 0; i < 32; i += 4)
    out[(size_t)(c0 + ty2 + i) * R + r0 + tx2] = f2bf(tile[ty2 + i][tx2]);
}

// ---------------- bf16 MFMA GEMM, 128x128 tile, BK=64, XOR swizzle ----------------
// Explicit LDS double-buffer: tile i+1's global_load_lds stay IN FLIGHT across
// the barrier (raw s_barrier + s_waitcnt vmcnt(8)); no full drain per K-step.
// XCD-band block mapping: block b -> xcd c=b%8 owns N-tiles [c*NYC,(c+1)*NYC).
// MODE 0: f32 store. MODE 1: fused-rope epilogue (q/k roped, v raw).
template <int MODE>
__global__ __launch_bounds__(256, 2)
void gemm_bt_kernel(const u16* __restrict__ A, const u16* __restrict__ B,
                    float* __restrict__ Cout, const int* __restrict__ positions,
                    u16* __restrict__ qb, u16* __restrict__ kb,
                    u16* __restrict__ vb, int K, int NKT, int Bvalid, int Nout,
                    int ldc, int NX, int NYC, int NY) {
  __shared__ __align__(16) u16 As[2][128 * 64];
  __shared__ __align__(16) u16 Bs[2][128 * 64];
  const int bb = blockIdx.x;
  const int xcd = bb & 7, bi = bb >> 3;
  const int ny = xcd * NYC + (bi % NYC);
  const int mx = bi / NYC;
  if (ny >= NY || mx >= NX) return;
  const int m0 = mx * 128, n0 = ny * 128;

  const int tid = threadIdx.x;
  const int lane = tid & 63, wave = tid >> 6;
  const int quad = lane >> 4, l16 = lane & 15;
  const int wm = wave >> 1, wn = wave & 1;

  const u16* Aptr[4]; const u16* Bptr[4];
  u16* Al[2][4]; u16* Bl[2][4];
#pragma unroll
  for (int it = 0; it < 4; ++it) {
    int c = it * 256 + tid;
    int r = c >> 3;
    int lcol = ((c & 7) ^ (r & 7)) * 8;           // XOR swizzle on GLOBAL side
    Aptr[it] = A + (size_t)(m0 + r) * K + lcol;
    int br = n0 + r; br = br < Bvalid ? br : Bvalid - 1;
    Bptr[it] = B + (size_t)br * K + lcol;
    Al[0][it] = &As[0][c * 8]; Al[1][it] = &As[1][c * 8];
    Bl[0][it] = &Bs[0][c * 8]; Bl[1][it] = &Bs[1][c * 8];
  }

  f32x4 acc[4][4] = {};
  const int sw0 = (quad ^ (l16 & 7)) * 8;

  // prologue: tile 0 -> buffer 0
#pragma unroll
  for (int it = 0; it < 4; ++it) gload16(Aptr[it], Al[0][it]);
#pragma unroll
  for (int it = 0; it < 4; ++it) gload16(Bptr[it], Bl[0][it]);

  int kt = 64;
  for (int t = 0; t < NKT - 1; ++t, kt += 64) {
    const int cur = t & 1, nxt = cur ^ 1;
    // issue next tile's loads (stay in flight across the barrier)
#pragma unroll
    for (int it = 0; it < 4; ++it) gload16(Aptr[it] + kt, Al[nxt][it]);
#pragma unroll
    for (int it = 0; it < 4; ++it) gload16(Bptr[it] + kt, Bl[nxt][it]);
    // wait only for CURRENT tile's 8 loads; 8 newer remain outstanding
    asm volatile("s_waitcnt vmcnt(8)\n\ts_barrier" ::: "memory");
    const u16* Ab = &As[cur][0];
    const u16* Bb = &Bs[cur][0];
#pragma unroll
    for (int kk = 0; kk < 2; ++kk) {
      const int swo = sw0 ^ (kk * 32);
      short8 af[4], bf[4];
#pragma unroll
      for (int i = 0; i < 4; ++i)
        af[i] = *(const short8*)(Ab + (wm * 64 + i * 16 + l16) * 64 + swo);
#pragma unroll
      for (int j = 0; j < 4; ++j)
        bf[j] = *(const short8*)(Bb + (wn * 64 + j * 16 + l16) * 64 + swo);
#pragma unroll
      for (int i = 0; i < 4; ++i)
#pragma unroll
        for (int j = 0; j < 4; ++j)
          acc[i][j] = __builtin_amdgcn_mfma_f32_16x16x32_bf16(af[i], bf[j], acc[i][j], 0, 0, 0);
    }
    // all waves done reading buf[cur] before it is refilled next iteration
    asm volatile("s_waitcnt lgkmcnt(0)\n\ts_barrier" ::: "memory");
  }
  {
    const int cur = (NKT - 1) & 1;
    asm volatile("s_waitcnt vmcnt(0)\n\ts_barrier" ::: "memory");
    const u16* Ab = &As[cur][0];
    const u16* Bb = &Bs[cur][0];
#pragma unroll
    for (int kk = 0; kk < 2; ++kk) {
      const int swo = sw0 ^ (kk * 32);
      short8 af[4], bf[4];
#pragma unroll
      for (int i = 0; i < 4; ++i)
        af[i] = *(const short8*)(Ab + (wm * 64 + i * 16 + l16) * 64 + swo);
#pragma unroll
      for (int j = 0; j < 4; ++j)
        bf[j] = *(const short8*)(Bb + (wn * 64 + j * 16 + l16) * 64 + swo);
#pragma unroll
      for (int i = 0; i < 4; ++i)
#pragma unroll
        for (int j = 0; j < 4; ++j)
          acc[i][j] = __builtin_amdgcn_mfma_f32_16x16x32_bf16(af[i], bf[j], acc[i][j], 0, 0, 0);
    }
  }

  if (MODE == 0) {
#pragma unroll
    for (int i = 0; i < 4; ++i) {
      const int row = m0 + wm * 64 + i * 16 + quad * 4;
#pragma unroll
      for (int j = 0; j < 4; ++j) {
        const int col = n0 + wn * 64 + j * 16 + l16;
        if (col < Nout)
#pragma unroll
          for (int r = 0; r < 4; ++r)
            Cout[(size_t)(row + r) * ldc + col] = acc[i][j][r];
      }
    }
  } else {
    const int region = (n0 < QSIZE) ? 0 : (n0 < QSIZE + KVSIZE ? 1 : 2);
    if (region <= 1) {
      float invs[2];
#pragma unroll
      for (int j = 0; j < 2; ++j)
        invs[j] = exp2f(-(float)(j * 16 + l16) * ROPE_L2);
#pragma unroll
      for (int i = 0; i < 4; ++i) {
#pragma unroll
        for (int r = 0; r < 4; ++r) {
          const int row = m0 + wm * 64 + i * 16 + quad * 4 + r;
          const float pos = (float)positions[row];
#pragma unroll
          for (int j = 0; j < 2; ++j) {
            float s, c;
            sincosf(pos * invs[j], &s, &c);
            const float x1 = acc[i][j][r], x2 = acc[i][j + 2][r];
            const float o1 = x1 * c - x2 * s, o2 = x2 * c + x1 * s;
            const int col = n0 + wn * 64 + j * 16 + l16;
            if (region == 0) {
              qb[(size_t)row * QSIZE + col] = f2bf(o1);
              qb[(size_t)row * QSIZE + col + 32] = f2bf(o2);
            } else {
              kb[(size_t)row * KVSIZE + col - QSIZE] = f2bf(o1);
              kb[(size_t)row * KVSIZE + col - QSIZE + 32] = f2bf(o2);
            }
          }
        }
      }
    } else {
#pragma unroll
      for (int i = 0; i < 4; ++i) {
        const int row = m0 + wm * 64 + i * 16 + quad * 4;
#pragma unroll
        for (int j = 0; j < 4; ++j) {
          const int col = n0 + wn * 64 + j * 16 + l16 - (QSIZE + KVSIZE);
#pragma unroll
          for (int r = 0; r < 4; ++r)
            vb[(size_t)(row + r) * KVSIZE + col] = f2bf(acc[i][j][r]);
        }
      }
    }
  }
}

// ---------------- windowed attention with sinks ----------------
__global__ __launch_bounds__(256, 2)
void attn_kernel(const u16* __restrict__ qb, const u16* __restrict__ kb,
                 const u16* __restrict__ vb, const float* __restrict__ sinks,
                 u16* __restrict__ attnb) {
  __shared__ __align__(16) u16 Ks[160 * 72];      // 23040 B
  __shared__ __align__(16) u16 Vt[64 * 164];      // 20992 B, V^T [dim][key]
  __shared__ __align__(16) u16 Pb[4 * 16 * 164];  // 20992 B, per-wave P (Vraw first)
  const int qt = blockIdx.x, g = blockIdx.y;
  const int q0 = qt * 32, kstart = q0 - 128;
  const int tid = threadIdx.x;
  const int lane = tid & 63, wave = tid >> 6;
  const int quad = lane >> 4, l16 = lane & 15;

  for (int s = tid; s < 1280; s += 256) {
    int r = s >> 3, c8 = (s & 7) * 8;
    int tg = kstart + r; tg = tg < 0 ? 0 : tg;
    *(short8*)(Ks + r * 72 + c8) =
        *(const short8*)(kb + (size_t)tg * KVSIZE + g * HD + c8);
  }
  {
    const u16* vbase = vb + g * HD;
#pragma unroll
    for (int it = 0; it < 5; ++it) {
      int s = it * 256 + tid;
      int r = s >> 3, c8 = (s & 7) * 8;
      int tg = kstart + r; tg = tg < 0 ? 0 : tg;
      gload16(vbase + (size_t)tg * KVSIZE + c8, Pb + s * 8);
    }
  }
  asm volatile("s_waitcnt vmcnt(0)" ::: "memory");
  __syncthreads();

  short8 bk[10][2];
#pragma unroll
  for (int jf = 0; jf < 10; ++jf)
#pragma unroll
    for (int kk = 0; kk < 2; ++kk)
      bk[jf][kk] = *(const short8*)(Ks + (jf * 16 + l16) * 72 + kk * 32 + quad * 8);

  for (int s = tid; s < 1280; s += 256) {
    int k8 = s >> 6, d = s & 63;
    short8 tmp;
#pragma unroll
    for (int j = 0; j < 8; ++j) tmp[j] = (short)Pb[(k8 * 8 + j) * 64 + d];
    *(short8*)(Vt + d * 164 + k8 * 8) = tmp;
  }
  __syncthreads();

  const int strip = wave & 1, hb = wave >> 1;
  const int qrow0 = q0 + strip * 16;
  u16* Pw = Pb + wave * 16 * 164;
  for (int hh = 0; hh < 4; ++hh) {
    const int h = g * 8 + hb + hh * 2;
    short8 aq[2];
#pragma unroll
    for (int kk = 0; kk < 2; ++kk)
      aq[kk] = *(const short8*)(qb + (size_t)(qrow0 + l16) * QSIZE + h * HD + kk * 32 + quad * 8);
    f32x4 sc[10];
#pragma unroll
    for (int jf = 0; jf < 10; ++jf) {
      f32x4 c = {0.f, 0.f, 0.f, 0.f};
#pragma unroll
      for (int kk = 0; kk < 2; ++kk)
        c = __builtin_amdgcn_mfma_f32_16x16x32_bf16(aq[kk], bk[jf][kk], c, 0, 0, 0);
      sc[jf] = c;
    }

    const float sink = sinks[h];
    float pinv[4];
#pragma unroll
    for (int r = 0; r < 4; ++r) {
      const int qg = qrow0 + quad * 4 + r;
      float mx = -3.0e38f;
#pragma unroll
      for (int jf = 0; jf < 10; ++jf) {
        int kg = kstart + jf * 16 + l16;
        bool valid = (kg >= 0) && (kg <= qg) && (qg - kg < WINDOW);
        float sv = valid ? sc[jf][r] * SCALE_F : -3.0e38f;
        sc[jf][r] = sv;
        mx = fmaxf(mx, sv);
      }
#pragma unroll
      for (int d = 1; d < 16; d <<= 1) mx = fmaxf(mx, __shfl_xor(mx, d, 64));
      mx = fmaxf(mx, sink);
      float sum = 0.f;
#pragma unroll
      for (int jf = 0; jf < 10; ++jf) {
        float e = __expf(sc[jf][r] - mx);
        sc[jf][r] = e;
        sum += e;
      }
#pragma unroll
      for (int d = 1; d < 16; d <<= 1) sum += __shfl_xor(sum, d, 64);
      sum += __expf(sink - mx);
      pinv[r] = 1.0f / sum;
    }

#pragma unroll
    for (int jf = 0; jf < 10; ++jf)
#pragma unroll
      for (int r = 0; r < 4; ++r)
        Pw[(quad * 4 + r) * 164 + jf * 16 + l16] = f2bf(sc[jf][r] * pinv[r]);

    f32x4 o[4] = {};
#pragma unroll
    for (int kk = 0; kk < 5; ++kk) {
      short8 ap = *(const short8*)(Pw + l16 * 164 + kk * 32 + quad * 8);
#pragma unroll
      for (int jf = 0; jf < 4; ++jf) {
        short8 bv = *(const short8*)(Vt + (jf * 16 + l16) * 164 + kk * 32 + quad * 8);
        o[jf] = __builtin_amdgcn_mfma_f32_16x16x32_bf16(ap, bv, o[jf], 0, 0, 0);
      }
    }
#pragma unroll
    for (int jf = 0; jf < 4; ++jf)
#pragma unroll
      for (int r = 0; r < 4; ++r) {
        int qg = qrow0 + quad * 4 + r;
        attnb[(size_t)qg * QSIZE + h * HD + jf * 16 + l16] = f2bf(o[jf][r]);
      }
  }
}

extern "C" void kernel_launch(void* const* d_in, const int* in_sizes, int n_in,
                              void* d_out, int out_size, void* d_ws, size_t ws_size,
                              hipStream_t stream) {
  (void)in_sizes; (void)n_in; (void)out_size; (void)ws_size;
  const int*   positions = (const int*)d_in[0];
  const float* hidden    = (const float*)d_in[1];
  const float* w_qkv     = (const float*)d_in[2];
  const float* w_o       = (const float*)d_in[3];
  const float* sinks     = (const float*)d_in[4];

  char* p = (char*)d_ws;
  u16* Xb    = (u16*)p; p += (size_t)T_SEQ * HIDDEN * 2;
  u16* Wqt   = (u16*)p; p += (size_t)QKV_N * HIDDEN * 2;
  u16* Wot   = (u16*)p; p += (size_t)HIDDEN * QSIZE * 2;
  u16* qb    = (u16*)p; p += (size_t)T_SEQ * QSIZE * 2;
  u16* kb    = (u16*)p; p += (size_t)T_SEQ * KVSIZE * 2;
  u16* vb    = (u16*)p; p += (size_t)T_SEQ * KVSIZE * 2;
  u16* attnb = (u16*)p; p += (size_t)T_SEQ * QSIZE * 2;

  prep_kernel<<<PREP_BLKS, 256, 0, stream>>>(hidden, w_qkv, w_o, Xb, Wqt, Wot);
  // GEMM1: M=2048(NX=16), N=5120(NY=40, NYC=5), K=2880 (NKT=45)
  gemm_bt_kernel<1><<<16 * 8 * 5, 256, 0, stream>>>(
      Xb, Wqt, nullptr, positions, qb, kb, vb,
      HIDDEN, 45, QKV_N, QKV_N, QKV_N, 16, 5, 40);
  attn_kernel<<<dim3(T_SEQ / 32, NKV), 256, 0, stream>>>(qb, kb, vb, sinks, attnb);
  // GEMM2: M=2048(NX=16), N=2880(NY=23, NYC=3), K=4096 (NKT=64)
  gemm_bt_kernel<0><<<16 * 8 * 3, 256, 0, stream>>>(
      attnb, Wot, (float*)d_out, nullptr, nullptr, nullptr, nullptr,
      QSIZE, 64, HIDDEN, HIDDEN, HIDDEN, 16, 3, 23);
}